// Round 8
// baseline (21253.627 us; speedup 1.0000x reference)
//
#include <hip/hip_runtime.h>

#define TRAJ 4
#define BATCH 256
#define DIM 256
#define HID 1024
#define NT 50
#define NSAMP (TRAJ*BATCH)   // 1024
#define MB 16                // samples per block
#define NBLK (NSAMP/MB)      // 64
#define NTHR 512             // 8 waves

// d_ws layout (ushort elems): per wave w (0..7): 384 fragments of 512 ushorts
// (1KB) in exact stream order: [L1: 64 frags][L2: 256][L3: 64].
// L1 f=g*8+ct (g k-slice 0..7, ct col-tile 0..7)
// L2 f=64+g*8+ct (g 0..31)
// L3 f=320+g*2+t  (g 0..31, t 0..1)
#define WAVE_WS 196608       // 384 frags * 512 ushorts

typedef __bf16 bf16x8 __attribute__((ext_vector_type(8)));
typedef float  f32x4  __attribute__((ext_vector_type(4)));
typedef unsigned int uint4v __attribute__((ext_vector_type(4)));

__device__ __forceinline__ unsigned short f2bf(float x) {
    unsigned int b = __float_as_uint(x);
    b += 0x7fffu + ((b >> 16) & 1u);   // round-to-nearest-even
    return (unsigned short)(b >> 16);
}

__device__ __forceinline__ float ftanh(float x) {
    float e = __expf(2.0f * x);
    return 1.0f - 2.0f * __builtin_amdgcn_rcpf(e + 1.0f);
}

__device__ __forceinline__ f32x4 mfma16(uint4v a, uint4v b, f32x4 c) {
    return __builtin_amdgcn_mfma_f32_16x16x32_bf16(
        __builtin_bit_cast(bf16x8, a), __builtin_bit_cast(bf16x8, b), c, 0, 0, 0);
}

// async global->LDS DMA: 16B per lane, LDS dest = wave-uniform base + lane*16
__device__ __forceinline__ void gld_lds16(const unsigned short* g, unsigned short* l) {
    __builtin_amdgcn_global_load_lds(
        (const __attribute__((address_space(1))) unsigned int*)g,
        (__attribute__((address_space(3))) unsigned int*)l, 16, 0, 0);
}

// ---------------------------------------------------------------------------
// Prep: swizzle f32 weights -> bf16 fragments in per-wave stream order.
// One 64-lane block per fragment; bid = w*384 + r.
// Fragment element j of lane l = W[g*32 + (l>>4)*8 + j][colbase + (l&15)]
// ---------------------------------------------------------------------------
__global__ void prep_kernel(const float* __restrict__ W1,
                            const float* __restrict__ W2,
                            const float* __restrict__ W3,
                            unsigned short* __restrict__ ws) {
    int bid  = blockIdx.x;           // 0..3071
    int lane = threadIdx.x;
    int w = bid / 384;
    int r = bid % 384;
    const float* W;
    int ncol, colbase, g;
    if (r < 64) {                    // L1
        W = W1; ncol = 1024; g = r >> 3;
        colbase = w * 128 + (r & 7) * 16;
    } else if (r < 320) {            // L2
        int q = r - 64;
        W = W2; ncol = 1024; g = q >> 3;
        colbase = w * 128 + (q & 7) * 16;
    } else {                         // L3
        int q = r - 320;
        W = W3; ncol = 256; g = q >> 1;
        colbase = w * 32 + (q & 1) * 16;
    }
    int col = colbase + (lane & 15);
    int k0  = g * 32 + (lane >> 4) * 8;
    unsigned short v[8];
#pragma unroll
    for (int j = 0; j < 8; ++j)
        v[j] = f2bf(W[(k0 + j) * ncol + col]);
    *(uint4v*)(ws + (size_t)bid * 512 + lane * 8) = *(const uint4v*)v;
}

// barrier draining LDS ops only; global DMA stays in flight
#define BAR() do { \
    asm volatile("s_waitcnt lgkmcnt(0)" ::: "memory"); \
    __builtin_amdgcn_s_barrier(); \
    asm volatile("" ::: "memory"); \
} while (0)

// wait: all but the newest 5 VMEM ops retired => frag f+1 landed in LDS
#define VMW5() asm volatile("s_waitcnt vmcnt(5)" ::: "memory")

// issue fragment ff (1KB) of this wave's stream into ring slot ff&7
// (384 % 8 == 0, so slot index is continuous across the stage wrap)
#define ISSUEF(ff) do { \
    const int _f = (ff) % 384; \
    gld_lds16(wlane + (size_t)_f * 512, ringw + (_f & 7) * 512); } while (0)

#define RDF(f) (*(const uint4v*)(ringw + ((f) & 7) * 512 + lane * 8))

// ---------------------------------------------------------------------------
// Main: persistent per-sample-block RK4 integrator. 64 blocks x 16 samples.
// Weights streamed via global_load_lds into per-wave 8-slot x 1KB LDS ring.
// Read-first / wait-for-next, fragment granularity, issue-ahead 6:
//   iter f: ds_read(frag f)   [landed: confirmed by iter f-1's vmcnt(5)]
//           ISSUE((f+6)%384)  [slot (f+6)&7 held frag f-2, read 2 iters ago:
//                              WAR margin 2 — R7's proven margin]
//           vmcnt(5)          [outstanding <= {f+2..f+6} -> f+1 retired]
//           MFMA(frag f)
// 384 frags/stage/wave; stream wraps across layers/stages/steps, no drain.
// In-flight ~5.5KB/wave x 8 waves ~ 44KB/CU (vs R7's 24KB) -> ~2x stream BW.
// ---------------------------------------------------------------------------
__global__ __launch_bounds__(NTHR, 2) void ode_main(
        const float* __restrict__ y0g, const float* __restrict__ ts,
        const float* __restrict__ b1g, const float* __restrict__ b2g,
        const float* __restrict__ b3g,
        const unsigned short* __restrict__ wsw, float* __restrict__ out) {

    __shared__ __align__(16) unsigned short ys[MB][DIM + 8];   // stage input
    __shared__ __align__(16) unsigned short h1[MB][HID + 8];
    __shared__ __align__(16) unsigned short h2[MB][HID + 8];
    __shared__ __align__(16) unsigned short ring[8][8][512];   // 64KB DMA ring

    const int tid  = threadIdx.x;
    const int wave = tid >> 6;
    const int lane = tid & 63;
    const int lr   = lane & 15;     // tile col (and A-row)
    const int lg   = lane >> 4;     // lane group: C rows lg*4..lg*4+3, A k-chunk
    const int s0   = blockIdx.x * MB;
    const int hc0  = wave * 128;    // this wave's H-column base (layers 1,2)
    const int dc0  = wave * 32;     // this wave's D-column base (layer 3 / y)

    const unsigned short* wlane = wsw + (size_t)wave * WAVE_WS + lane * 8;
    unsigned short* ringw = &ring[wave][0][0];

    // biases
    float bias1[8], bias2[8], bias3[2];
#pragma unroll
    for (int t = 0; t < 8; ++t) {
        bias1[t] = b1g[hc0 + t * 16 + lr];
        bias2[t] = b2g[hc0 + t * 16 + lr];
    }
    bias3[0] = b3g[dc0 + lr];
    bias3[1] = b3g[dc0 + 16 + lr];

    // init: y registers, seed ys LDS, write out[t=0]
    float yreg[2][4];
#pragma unroll
    for (int t = 0; t < 2; ++t)
#pragma unroll
        for (int j = 0; j < 4; ++j) {
            int row = lg * 4 + j, col = dc0 + t * 16 + lr;
            float v = y0g[(s0 + row) * DIM + col];
            yreg[t][j] = v;
            ys[row][col] = f2bf(v);
            __builtin_nontemporal_store(v, &out[((s0 + row) * NT + 0) * DIM + col]);
        }
    __syncthreads();   // full drain before the pipeline starts

    float acc[2][4];
    const f32x4 z4 = {0.f, 0.f, 0.f, 0.f};

    // prologue: 6 frags ahead; vmcnt(5) => frag 0 landed
    ISSUEF(0); ISSUEF(1); ISSUEF(2); ISSUEF(3); ISSUEF(4); ISSUEF(5);
    VMW5();

#pragma unroll 1
    for (int step = 1; step < NT; ++step) {
        float dt = ts[step] - ts[step - 1];
#pragma unroll 1
        for (int stage = 0; stage < 4; ++stage) {
            // ======== layer 1: h1 = tanh(ys @ W1 + b1) — frags 0..63 =========
            {
                f32x4 c1[8];
#pragma unroll
                for (int c = 0; c < 8; ++c) c1[c] = z4;
#pragma unroll
                for (int g = 0; g < 8; ++g) {
                    uint4v a1 = *(const uint4v*)&ys[lr][g * 32 + lg * 8];
#pragma unroll
                    for (int ct = 0; ct < 8; ++ct) {
                        const int f = g * 8 + ct;
                        uint4v b = RDF(f);
                        ISSUEF(f + 6);
                        VMW5();
                        c1[ct] = mfma16(a1, b, c1[ct]);
                    }
                }
#pragma unroll
                for (int c = 0; c < 8; ++c)
#pragma unroll
                    for (int j = 0; j < 4; ++j)
                        h1[lg * 4 + j][hc0 + c * 16 + lr] = f2bf(ftanh(c1[c][j] + bias1[c]));
            }
            BAR();

            // ======== layer 2: h2 = tanh(h1 @ W2 + b2) — frags 64..319 =======
            {
                f32x4 c2[8];
#pragma unroll
                for (int c = 0; c < 8; ++c) c2[c] = z4;
#pragma unroll
                for (int g = 0; g < 32; ++g) {
                    uint4v a = *(const uint4v*)&h1[lr][g * 32 + lg * 8];
#pragma unroll
                    for (int ct = 0; ct < 8; ++ct) {
                        const int f = 64 + g * 8 + ct;
                        uint4v b = RDF(f);
                        ISSUEF(f + 6);
                        VMW5();
                        c2[ct] = mfma16(a, b, c2[ct]);
                    }
                }
#pragma unroll
                for (int c = 0; c < 8; ++c)
#pragma unroll
                    for (int j = 0; j < 4; ++j)
                        h2[lg * 4 + j][hc0 + c * 16 + lr] = f2bf(ftanh(c2[c][j] + bias2[c]));
            }
            BAR();

            // ======== layer 3: k = h2 @ W3 + b3 — frags 320..383 (wraps) =====
            {
                f32x4 c30 = z4, c31 = z4;
#pragma unroll
                for (int g = 0; g < 32; ++g) {
                    uint4v a = *(const uint4v*)&h2[lr][g * 32 + lg * 8];
                    {
                        const int f = 320 + g * 2;
                        uint4v b = RDF(f);
                        ISSUEF(f + 6);
                        VMW5();
                        c30 = mfma16(a, b, c30);
                    }
                    {
                        const int f = 321 + g * 2;
                        uint4v b = RDF(f);
                        ISSUEF(f + 6);
                        VMW5();
                        c31 = mfma16(a, b, c31);
                    }
                }

                float accw = (stage == 0 || stage == 3) ? 1.0f : 2.0f;
                float cin  = (stage == 2) ? dt : 0.5f * dt;
                f32x4 c3p[2]; c3p[0] = c30; c3p[1] = c31;
#pragma unroll
                for (int t = 0; t < 2; ++t)
#pragma unroll
                    for (int j = 0; j < 4; ++j) {
                        float kv = c3p[t][j] + bias3[t];
                        acc[t][j] = (stage == 0) ? kv : acc[t][j] + accw * kv;
                        float ysv;
                        if (stage < 3) {
                            ysv = yreg[t][j] + cin * kv;
                        } else {
                            yreg[t][j] += dt * (1.0f / 6.0f) * acc[t][j];
                            ysv = yreg[t][j];
                            __builtin_nontemporal_store(
                                ysv, &out[((s0 + lg * 4 + j) * NT + step) * DIM + dc0 + t * 16 + lr]);
                        }
                        ys[lg * 4 + j][dc0 + t * 16 + lr] = f2bf(ysv);
                    }
            }
            BAR();
        }
    }
    // drain outstanding DMA before wave exit
    asm volatile("s_waitcnt vmcnt(0)" ::: "memory");
}

extern "C" void kernel_launch(void* const* d_in, const int* in_sizes, int n_in,
                              void* d_out, int out_size, void* d_ws, size_t ws_size,
                              hipStream_t stream) {
    const float* y0 = (const float*)d_in[0];
    const float* ts = (const float*)d_in[1];
    const float* W1 = (const float*)d_in[2];
    const float* b1 = (const float*)d_in[3];
    const float* W2 = (const float*)d_in[4];
    const float* b2 = (const float*)d_in[5];
    const float* W3 = (const float*)d_in[6];
    const float* b3 = (const float*)d_in[7];
    unsigned short* ws = (unsigned short*)d_ws;
    float* out = (float*)d_out;

    prep_kernel<<<3072, 64, 0, stream>>>(W1, W2, W3, ws);
    ode_main<<<NBLK, NTHR, 0, stream>>>(y0, ts, b1, b2, b3, ws, out);
}

// Round 9
// 3350.470 us; speedup vs baseline: 6.3435x; 6.3435x over previous
//
#include <hip/hip_runtime.h>

#define TRAJ 4
#define BATCH 256
#define DIM 256
#define HID 1024
#define NT 50
#define NSAMP (TRAJ*BATCH)   // 1024
#define MB 16                // samples per pair
#define NPAIR 64
#define NBLK 128             // 2 blocks (H-halves) per pair
#define NTHR 512             // 8 waves

// per-wave weight stream: 224 frags x 1KB in stage order
//   [L1 full  : 64  = g(8) x ct(8), cols w*128+ct*16          ]
//   [L2 half  : 128 = g(32) x ct(4), cols hf*512+w*64+ct*16   ]
//   [L3 K-half: 32  = g(16) x t(2),  rows hf*512+g*32, cols w*32+t*16]
#define FR_PER_WAVE 224
#define WAVE_STREAM_US (FR_PER_WAVE*512)          // ushorts per wave stream
#define EX_OFF_BYTES 3670016                      // 2*8*224KB = 3.5MB weights
#define EX_SLOT_F 4096                            // 16KB per (block,par) slot
#define FLG_OFF_BYTES (EX_OFF_BYTES + 64*2*2*16384)   // +4MB exchange bufs

typedef __bf16 bf16x8 __attribute__((ext_vector_type(8)));
typedef float  f32x4  __attribute__((ext_vector_type(4)));
typedef unsigned int uint4v __attribute__((ext_vector_type(4)));

__device__ __forceinline__ unsigned short f2bf(float x) {
    unsigned int b = __float_as_uint(x);
    b += 0x7fffu + ((b >> 16) & 1u);
    return (unsigned short)(b >> 16);
}

__device__ __forceinline__ float ftanh(float x) {
    float e = __expf(2.0f * x);
    return 1.0f - 2.0f * __builtin_amdgcn_rcpf(e + 1.0f);
}

__device__ __forceinline__ f32x4 mfma16(uint4v a, uint4v b, f32x4 c) {
    return __builtin_amdgcn_mfma_f32_16x16x32_bf16(
        __builtin_bit_cast(bf16x8, a), __builtin_bit_cast(bf16x8, b), c, 0, 0, 0);
}

__device__ __forceinline__ void gld_lds16(const unsigned short* g, unsigned short* l) {
    __builtin_amdgcn_global_load_lds(
        (const __attribute__((address_space(1))) unsigned int*)g,
        (__attribute__((address_space(3))) unsigned int*)l, 16, 0, 0);
}

// coherence-point (bypass L1/L2 cached path) stores/loads for the exchange —
// avoids acquire-invalidates that would evict the L2-resident weight stream.
__device__ __forceinline__ void store_sc2(float* p0, f32x4 v0, float* p1, f32x4 v1) {
    asm volatile("global_store_dwordx4 %0, %1, off sc0 sc1\n\t"
                 "global_store_dwordx4 %2, %3, off sc0 sc1"
                 :: "v"(p0), "v"(v0), "v"(p1), "v"(v1) : "memory");
}
__device__ __forceinline__ void load_sc2(const float* p0, const float* p1,
                                         f32x4* r0, f32x4* r1) {
    f32x4 a, b;
    asm volatile("global_load_dwordx4 %0, %2, off sc0 sc1\n\t"
                 "global_load_dwordx4 %1, %3, off sc0 sc1\n\t"
                 "s_waitcnt vmcnt(0)"
                 : "=&v"(a), "=&v"(b) : "v"(p0), "v"(p1) : "memory");
    *r0 = a; *r1 = b;
}

// ---------------------------------------------------------------------------
__global__ void zero_flags(unsigned int* flg) {
    if (threadIdx.x < 256)
        __hip_atomic_store(&flg[threadIdx.x], 0u, __ATOMIC_RELAXED,
                           __HIP_MEMORY_SCOPE_AGENT);
}

// ---------------------------------------------------------------------------
// Prep: bid = hf*1792 + w*224 + f  (3584 blocks x 64 lanes)
// ---------------------------------------------------------------------------
__global__ void prep_kernel(const float* __restrict__ W1,
                            const float* __restrict__ W2,
                            const float* __restrict__ W3,
                            unsigned short* __restrict__ ws) {
    int bid  = blockIdx.x;
    int lane = threadIdx.x;
    int hf = bid / 1792;
    int rem = bid % 1792;
    int w = rem / 224;
    int f = rem % 224;
    const float* W;
    int ncol, col, k0;
    if (f < 64) {                        // L1 full
        int g = f >> 3, ct = f & 7;
        W = W1; ncol = 1024;
        col = w * 128 + ct * 16 + (lane & 15);
        k0  = g * 32 + (lane >> 4) * 8;
    } else if (f < 192) {                // L2 col-half
        int q = f - 64, g = q >> 2, ct = q & 3;
        W = W2; ncol = 1024;
        col = hf * 512 + w * 64 + ct * 16 + (lane & 15);
        k0  = g * 32 + (lane >> 4) * 8;
    } else {                             // L3 K-half
        int q = f - 192, g = q >> 1, t = q & 1;
        W = W3; ncol = 256;
        col = w * 32 + t * 16 + (lane & 15);
        k0  = hf * 512 + g * 32 + (lane >> 4) * 8;
    }
    unsigned short v[8];
#pragma unroll
    for (int j = 0; j < 8; ++j)
        v[j] = f2bf(W[(k0 + j) * ncol + col]);
    *(uint4v*)(ws + ((size_t)(hf * 8 + w) * 224 + f) * 512 + lane * 8) =
        *(const uint4v*)v;
}

// barrier draining LDS ops only; global DMA stays in flight
#define BAR() do { \
    asm volatile("s_waitcnt lgkmcnt(0)" ::: "memory"); \
    __builtin_amdgcn_s_barrier(); \
    asm volatile("" ::: "memory"); \
} while (0)

#define VMW2() asm volatile("s_waitcnt vmcnt(2)" ::: "memory")

// issue chunk cc (2 frags = 2KB) into ring slot cc&3   (112 % 4 == 0)
#define ISSUE(cc) do { \
    const unsigned short* _s = wlane + (size_t)(cc) * 1024; \
    unsigned short* _d = ringw + ((cc) & 3) * 1024; \
    gld_lds16(_s, _d); \
    gld_lds16(_s + 512, _d + 512); \
} while (0)

#define RD(slot, fi) (*(const uint4v*)(ringw + (slot) * 1024 + (fi) * 512 + lane * 8))

// ---------------------------------------------------------------------------
// Main: 64 pairs x 2 H-half blocks, 16 samples/pair, 8 waves/block.
// R7's proven ring schedule (2KB chunks, ahead-2, vmcnt(2)), 112 chunks/stage.
// One f32 k-partial exchange per stage via coherence-point stores + flags.
// ---------------------------------------------------------------------------
__global__ __launch_bounds__(NTHR, 2) void ode_main(
        const float* __restrict__ y0g, const float* __restrict__ ts,
        const float* __restrict__ b1g, const float* __restrict__ b2g,
        const float* __restrict__ b3g,
        unsigned short* __restrict__ wsv, float* __restrict__ out) {

    __shared__ __align__(16) unsigned short ys[MB][DIM + 8];   // 8.25KB
    __shared__ __align__(16) unsigned short h1[MB][HID + 8];   // 32.25KB (full)
    __shared__ __align__(16) unsigned short h2[MB][512 + 8];   // 16.25KB (half)
    __shared__ __align__(16) unsigned short ring[8][4][1024];  // 64KB

    const unsigned short* wsw = wsv;
    float* exch = (float*)((char*)wsv + EX_OFF_BYTES);
    unsigned int* flg = (unsigned int*)((char*)wsv + FLG_OFF_BYTES);

    const int tid  = threadIdx.x;
    const int wave = tid >> 6;
    const int lane = tid & 63;
    const int lr   = lane & 15;
    const int lg   = lane >> 4;
    const int pair = blockIdx.x >> 1;
    const int hf   = blockIdx.x & 1;
    const int s0   = pair * MB;
    const int dc0  = wave * 32;          // D cols (L3 / y / out)

    const unsigned short* wlane =
        wsw + (size_t)(hf * 8 + wave) * WAVE_STREAM_US + lane * 8;
    unsigned short* ringw = &ring[wave][0][0];

    // biases
    float bias1[8], bias2[4], bias3[2];
#pragma unroll
    for (int t = 0; t < 8; ++t) bias1[t] = b1g[wave * 128 + t * 16 + lr];
#pragma unroll
    for (int t = 0; t < 4; ++t) bias2[t] = b2g[hf * 512 + wave * 64 + t * 16 + lr];
    bias3[0] = b3g[dc0 + lr];
    bias3[1] = b3g[dc0 + 16 + lr];

    // init y
    float yreg[2][4];
#pragma unroll
    for (int t = 0; t < 2; ++t)
#pragma unroll
        for (int j = 0; j < 4; ++j) {
            int row = lg * 4 + j, col = dc0 + t * 16 + lr;
            float v = y0g[(s0 + row) * DIM + col];
            yreg[t][j] = v;
            ys[row][col] = f2bf(v);
            if (hf == 0)
                __builtin_nontemporal_store(v, &out[((s0 + row) * NT + 0) * DIM + col]);
        }
    __syncthreads();

    float acc[2][4];
    const f32x4 z4 = {0.f, 0.f, 0.f, 0.f};

    ISSUE(0); ISSUE(1);
    VMW2();

#pragma unroll 1
    for (int step = 1; step < NT; ++step) {
        float dt = ts[step] - ts[step - 1];
#pragma unroll 1
        for (int stage = 0; stage < 4; ++stage) {
            const int tglob = (step - 1) * 4 + stage;
            const int par = tglob & 1;

            // ==== layer 1 (full H): h1 = tanh(ys@W1+b1) — chunks 0..31 ======
            {
                f32x4 c1[8];
#pragma unroll
                for (int c = 0; c < 8; ++c) c1[c] = z4;
#pragma unroll
                for (int g = 0; g < 8; ++g) {
                    uint4v a1 = *(const uint4v*)&ys[lr][g * 32 + lg * 8];
#pragma unroll
                    for (int p = 0; p < 4; ++p) {
                        const int c = g * 4 + p;
                        uint4v b0 = RD(c & 3, 0), b1 = RD(c & 3, 1);
                        ISSUE(c + 2);
                        VMW2();
                        c1[2 * p]     = mfma16(a1, b0, c1[2 * p]);
                        c1[2 * p + 1] = mfma16(a1, b1, c1[2 * p + 1]);
                    }
                }
#pragma unroll
                for (int c = 0; c < 8; ++c)
#pragma unroll
                    for (int j = 0; j < 4; ++j)
                        h1[lg * 4 + j][wave * 128 + c * 16 + lr] =
                            f2bf(ftanh(c1[c][j] + bias1[c]));
            }
            BAR();

            // ==== layer 2 (col-half): chunks 32..95 =========================
            {
                f32x4 c2[4];
#pragma unroll
                for (int c = 0; c < 4; ++c) c2[c] = z4;
#pragma unroll 4
                for (int g = 0; g < 32; ++g) {
                    uint4v a = *(const uint4v*)&h1[lr][g * 32 + lg * 8];
#pragma unroll
                    for (int p = 0; p < 2; ++p) {
                        const int c = 32 + g * 2 + p;
                        uint4v b0 = RD(c & 3, 0), b1 = RD(c & 3, 1);
                        ISSUE(c + 2);
                        VMW2();
                        c2[2 * p]     = mfma16(a, b0, c2[2 * p]);
                        c2[2 * p + 1] = mfma16(a, b1, c2[2 * p + 1]);
                    }
                }
#pragma unroll
                for (int c = 0; c < 4; ++c)
#pragma unroll
                    for (int j = 0; j < 4; ++j)
                        h2[lg * 4 + j][wave * 64 + c * 16 + lr] =
                            f2bf(ftanh(c2[c][j] + bias2[c]));
            }
            BAR();

            // ==== layer 3 (K-half partial): chunks 96..111 (wraps) ==========
            f32x4 c30 = z4, c31 = z4;
#pragma unroll 4
            for (int g = 0; g < 16; ++g) {
                uint4v a = *(const uint4v*)&h2[lr][g * 32 + lg * 8];
                const int c = 96 + g;
                uint4v b0 = RD(c & 3, 0), b1 = RD(c & 3, 1);
                int cc = (g < 14) ? (c + 2) : (g - 14);   // wrap to next stage
                ISSUE(cc);
                VMW2();
                c30 = mfma16(a, b0, c30);
                c31 = mfma16(a, b1, c31);
            }

            // ==== exchange k-partials with partner block ====================
            {
                const int myb = (pair * 2 + hf) * 2 + par;
                const int pnb = (pair * 2 + (1 - hf)) * 2 + par;
                float* mb = exch + (size_t)myb * EX_SLOT_F;
                store_sc2(mb + ((wave * 2 + 0) * 64 + lane) * 4, c30,
                          mb + ((wave * 2 + 1) * 64 + lane) * 4, c31);
                asm volatile("s_waitcnt vmcnt(0)" ::: "memory");
                __syncthreads();
                if (tid == 0) {
                    unsigned exp = (unsigned)(tglob >> 1) + 1u;
                    __hip_atomic_fetch_add(&flg[myb], 1u, __ATOMIC_RELAXED,
                                           __HIP_MEMORY_SCOPE_AGENT);
                    while (__hip_atomic_load(&flg[pnb], __ATOMIC_RELAXED,
                                             __HIP_MEMORY_SCOPE_AGENT) < exp)
                        __builtin_amdgcn_s_sleep(2);
                }
                __syncthreads();
                const float* pb = exch + (size_t)pnb * EX_SLOT_F;
                f32x4 r0, r1;
                load_sc2(pb + ((wave * 2 + 0) * 64 + lane) * 4,
                         pb + ((wave * 2 + 1) * 64 + lane) * 4, &r0, &r1);

                float accw = (stage == 0 || stage == 3) ? 1.0f : 2.0f;
                float cin  = (stage == 2) ? dt : 0.5f * dt;
                f32x4 own[2]; own[0] = c30; own[1] = c31;
                f32x4 oth[2]; oth[0] = r0;  oth[1] = r1;
#pragma unroll
                for (int t = 0; t < 2; ++t)
#pragma unroll
                    for (int j = 0; j < 4; ++j) {
                        float kv = own[t][j] + oth[t][j] + bias3[t];
                        acc[t][j] = (stage == 0) ? kv : acc[t][j] + accw * kv;
                        float ysv;
                        if (stage < 3) {
                            ysv = yreg[t][j] + cin * kv;
                        } else {
                            yreg[t][j] += dt * (1.0f / 6.0f) * acc[t][j];
                            ysv = yreg[t][j];
                            if (hf == 0)
                                __builtin_nontemporal_store(
                                    ysv, &out[((s0 + lg * 4 + j) * NT + step) * DIM +
                                              dc0 + t * 16 + lr]);
                        }
                        ys[lg * 4 + j][dc0 + t * 16 + lr] = f2bf(ysv);
                    }
            }
            BAR();
        }
    }
    asm volatile("s_waitcnt vmcnt(0)" ::: "memory");
}

extern "C" void kernel_launch(void* const* d_in, const int* in_sizes, int n_in,
                              void* d_out, int out_size, void* d_ws, size_t ws_size,
                              hipStream_t stream) {
    const float* y0 = (const float*)d_in[0];
    const float* ts = (const float*)d_in[1];
    const float* W1 = (const float*)d_in[2];
    const float* b1 = (const float*)d_in[3];
    const float* W2 = (const float*)d_in[4];
    const float* b2 = (const float*)d_in[5];
    const float* W3 = (const float*)d_in[6];
    const float* b3 = (const float*)d_in[7];
    unsigned short* ws = (unsigned short*)d_ws;
    float* out = (float*)d_out;

    zero_flags<<<1, 256, 0, stream>>>((unsigned int*)((char*)d_ws + FLG_OFF_BYTES));
    prep_kernel<<<3584, 64, 0, stream>>>(W1, W2, W3, ws);
    ode_main<<<NBLK, NTHR, 0, stream>>>(y0, ts, b1, b2, b3, ws, out);
}